// Round 5
// baseline (367.426 us; speedup 1.0000x reference)
//
#include <hip/hip_runtime.h>
#include <math.h>

#define NROWS 4096
#define DDIM  1024

typedef __attribute__((ext_vector_type(8))) short short8;
typedef __attribute__((ext_vector_type(4))) float f32x4;

// ---------- bf16 helpers (manual RNE) ----------
__device__ __forceinline__ ushort f2bf(float v) {
  union { float f; uint32_t u; } c; c.f = v;
  uint32_t u = c.u;
  uint32_t lsb = (u >> 16) & 1u;
  u += 0x7fffu + lsb;
  return (ushort)(u >> 16);
}
__device__ __forceinline__ float bf2f(ushort h) {
  union { uint32_t u; float f; } c; c.u = ((uint32_t)h) << 16;
  return c.f;
}

// ---------- async global->LDS, 16B per lane ----------
__device__ __forceinline__ void gll16(const void* g, void* l) {
  __builtin_amdgcn_global_load_lds((const __attribute__((address_space(1))) void*)g,
                                   (__attribute__((address_space(3))) void*)l, 16, 0, 0);
}

// ---------- prep: split x (blocks 0..1023) + transpose/split 3 weights (blocks 1024..4095) ----------
__global__ __launch_bounds__(256) void prep(const float* __restrict__ x,
                                            const float* __restrict__ wq,
                                            const float* __restrict__ wk,
                                            const float* __restrict__ wv,
                                            ushort* Xh, ushort* Xl,
                                            ushort* Wqh, ushort* Wql,
                                            ushort* Wkh, ushort* Wkl, ushort* Wvh) {
  __shared__ float tl[32][33];
  const int b = blockIdx.x, t = threadIdx.x;
  if (b < 1024) {
    const float4* src = (const float4*)x;
    ushort4* hi = (ushort4*)Xh;
    ushort4* lo = (ushort4*)Xl;
#pragma unroll
    for (int r = 0; r < 4; ++r) {
      int i = b * 1024 + r * 256 + t;  // 1M float4 total
      float4 v = src[i];
      ushort4 h, l;
      h.x = f2bf(v.x); l.x = f2bf(v.x - bf2f(h.x));
      h.y = f2bf(v.y); l.y = f2bf(v.y - bf2f(h.y));
      h.z = f2bf(v.z); l.z = f2bf(v.z - bf2f(h.z));
      h.w = f2bf(v.w); l.w = f2bf(v.w - bf2f(h.w));
      hi[i] = h; lo[i] = l;
    }
  } else {
    const int z = (b - 1024) >> 10;        // which weight
    const int tile = (b - 1024) & 1023;    // 32x32 tile index
    const float* src = z == 0 ? wq : (z == 1 ? wk : wv);
    ushort* dh = z == 0 ? Wqh : (z == 1 ? Wkh : Wvh);
    ushort* dl = z == 0 ? Wql : (z == 1 ? Wkl : nullptr);
    const int r0 = (tile >> 5) * 32;       // source row block (k)
    const int c0 = (tile & 31) * 32;       // source col block (n)
    const int tx = t & 31, ty = t >> 5;    // 32 x 8
    for (int i = ty; i < 32; i += 8)
      tl[i][tx] = src[(size_t)(r0 + i) * DDIM + c0 + tx];
    __syncthreads();
    for (int i = ty; i < 32; i += 8) {
      float v = tl[tx][i];                 // src[r0+tx][c0+i]
      ushort h = f2bf(v);
      size_t o = (size_t)(c0 + i) * DDIM + r0 + tx;
      dh[o] = h;
      if (dl) dl[o] = f2bf(v - bf2f(h));
    }
  }
}

// ---------- NT GEMM core: acc += A[M][K(kbeg..kend)] * B[N][K]^T ----------
// LDS: per tile row (64B), chunk q holds global quad (q ^ ((row>>1)&3)) -> conflict-free reads
template <int BM, bool SPLIT>
__device__ __forceinline__ void gemm_core(const ushort* __restrict__ Ah,
                                          const ushort* __restrict__ Al,
                                          const ushort* __restrict__ Bh,
                                          const ushort* __restrict__ Bl,
                                          int lda, int ldb, int kbeg, int kend,
                                          int m0, int n0, ushort* sm,
                                          f32x4 (*acc)[4]) {
  constexpr int MI = BM / 32;           // m-fragments per wave
  constexpr int ATILE = BM * 32;        // ushorts
  constexpr int BTILE = 128 * 32;
  ushort* sAh = sm;
  ushort* sAl = SPLIT ? sm + ATILE : nullptr;
  ushort* sBh = sm + (SPLIT ? 2 * ATILE : ATILE);
  ushort* sBl = SPLIT ? sBh + BTILE : nullptr;

  const int t = threadIdx.x;
  const int wv = t >> 6, ln = t & 63;
  const int quad = ln >> 4, l16 = ln & 15;
  const int key = (l16 >> 1) & 3;
  const int arb = (wv >> 1) * (BM / 2);
  const int crb = (wv & 1) * 64;

  for (int k0 = kbeg; k0 < kend; k0 += 32) {
#pragma unroll
    for (int r = 0; r < BM * 64 / 4096; ++r) {
      int f = t * 16 + r * 4096;                      // byte offset in A tile
      int row = f >> 6;
      int srcq = ((f >> 4) & 3) ^ ((row >> 1) & 3);   // swizzled source chunk
      size_t go = (size_t)(m0 + row) * lda + k0 + srcq * 8;
      gll16(Ah + go, sAh + (f >> 1));
      if (SPLIT) gll16(Al + go, sAl + (f >> 1));
    }
#pragma unroll
    for (int r = 0; r < 2; ++r) {
      int f = t * 16 + r * 4096;
      int row = f >> 6;
      int srcq = ((f >> 4) & 3) ^ ((row >> 1) & 3);
      size_t go = (size_t)(n0 + row) * ldb + k0 + srcq * 8;
      gll16(Bh + go, sBh + (f >> 1));
      if (SPLIT) gll16(Bl + go, sBl + (f >> 1));
    }
    __syncthreads();

    short8 ah[MI], bh[4], al[MI], bl[4];
#pragma unroll
    for (int i = 0; i < MI; ++i) {
      int off = (arb + i * 16 + l16) * 32 + (quad ^ key) * 8;
      ah[i] = *(const short8*)(sAh + off);
      if (SPLIT) al[i] = *(const short8*)(sAl + off);
    }
#pragma unroll
    for (int j = 0; j < 4; ++j) {
      int off = (crb + j * 16 + l16) * 32 + (quad ^ key) * 8;
      bh[j] = *(const short8*)(sBh + off);
      if (SPLIT) bl[j] = *(const short8*)(sBl + off);
    }
#pragma unroll
    for (int i = 0; i < MI; ++i)
#pragma unroll
      for (int j = 0; j < 4; ++j) {
        acc[i][j] = __builtin_amdgcn_mfma_f32_16x16x32_bf16(ah[i], bh[j], acc[i][j], 0, 0, 0);
        if (SPLIT) {
          acc[i][j] = __builtin_amdgcn_mfma_f32_16x16x32_bf16(ah[i], bl[j], acc[i][j], 0, 0, 0);
          acc[i][j] = __builtin_amdgcn_mfma_f32_16x16x32_bf16(al[i], bh[j], acc[i][j], 0, 0, 0);
        }
      }
    __syncthreads();
  }
}

// ---------- fused QKV: Q,K split-precision; V computed directly transposed ----------
__global__ __launch_bounds__(256) void gemm_qkv(const ushort* __restrict__ Xh,
                                                const ushort* __restrict__ Xl,
                                                const ushort* __restrict__ Wqh, const ushort* __restrict__ Wql,
                                                const ushort* __restrict__ Wkh, const ushort* __restrict__ Wkl,
                                                const ushort* __restrict__ Wvh,
                                                ushort* Qh, ushort* Ql, ushort* Kh, ushort* Kl, ushort* Vt) {
  extern __shared__ ushort sm[];
  const int which = blockIdx.x % 3;
  const int g = blockIdx.x / 3;              // 0..7
  const int t = threadIdx.x;
  const int wv = t >> 6, ln = t & 63;
  const int quad = ln >> 4, l16 = ln & 15;

  f32x4 acc[4][4];
#pragma unroll
  for (int i = 0; i < 4; ++i)
#pragma unroll
    for (int j = 0; j < 4; ++j) acc[i][j] = (f32x4){0.f, 0.f, 0.f, 0.f};

  if (which == 2) {
    // Vt[i][j] = sum_k Wvh[i][k] * Xh[j][k]  (= V[j][i])
    const int m0 = g * 128;                  // over 1024
    const int n0 = blockIdx.y * 128;         // over 4096
    gemm_core<128, false>(Wvh, nullptr, Xh, nullptr, DDIM, DDIM, 0, DDIM, m0, n0, sm, acc);
#pragma unroll
    for (int i = 0; i < 4; ++i)
#pragma unroll
      for (int j = 0; j < 4; ++j) {
        int col = n0 + (wv & 1) * 64 + j * 16 + l16;
        int rw = m0 + (wv >> 1) * 64 + i * 16 + quad * 4;
#pragma unroll
        for (int r2 = 0; r2 < 4; ++r2)
          Vt[(size_t)(rw + r2) * NROWS + col] = f2bf(acc[i][j][r2]);
      }
  } else {
    const int n0 = g * 128;                  // over 1024
    const int m0 = blockIdx.y * 128;         // over 4096
    const ushort* Bh = which ? Wkh : Wqh;
    const ushort* Bl = which ? Wkl : Wql;
    gemm_core<128, true>(Xh, Xl, Bh, Bl, DDIM, DDIM, 0, DDIM, m0, n0, sm, acc);
    const float scale = which ? 1.0f : 0.03125f;  // fold 1/sqrt(1024) into Q (exact pow2)
    ushort* H = which ? Kh : Qh;
    ushort* L = which ? Kl : Ql;
#pragma unroll
    for (int i = 0; i < 4; ++i)
#pragma unroll
      for (int j = 0; j < 4; ++j) {
        int col = n0 + (wv & 1) * 64 + j * 16 + l16;
        int rw = m0 + (wv >> 1) * 64 + i * 16 + quad * 4;
#pragma unroll
        for (int r2 = 0; r2 < 4; ++r2) {
          float v = acc[i][j][r2] * scale;
          ushort h = f2bf(v);
          size_t o = (size_t)(rw + r2) * DDIM + col;
          H[o] = h;
          L[o] = f2bf(v - bf2f(h));
        }
      }
  }
}

// ---------- S = Q*K^T (split precision), fp32 out ----------
__global__ __launch_bounds__(256) void gemm_s(const ushort* __restrict__ Qh, const ushort* __restrict__ Ql,
                                              const ushort* __restrict__ Kh, const ushort* __restrict__ Kl,
                                              float* __restrict__ S) {
  extern __shared__ ushort sm[];
  const int n0 = blockIdx.x * 128, m0 = blockIdx.y * 128;
  const int t = threadIdx.x;
  const int wv = t >> 6, ln = t & 63;
  const int quad = ln >> 4, l16 = ln & 15;
  f32x4 acc[4][4];
#pragma unroll
  for (int i = 0; i < 4; ++i)
#pragma unroll
    for (int j = 0; j < 4; ++j) acc[i][j] = (f32x4){0.f, 0.f, 0.f, 0.f};
  gemm_core<128, true>(Qh, Ql, Kh, Kl, DDIM, DDIM, 0, DDIM, m0, n0, sm, acc);
#pragma unroll
  for (int i = 0; i < 4; ++i)
#pragma unroll
    for (int j = 0; j < 4; ++j) {
      int col = n0 + (wv & 1) * 64 + j * 16 + l16;
      int rw = m0 + (wv >> 1) * 64 + i * 16 + quad * 4;
#pragma unroll
      for (int r2 = 0; r2 < 4; ++r2)
        S[(size_t)(rw + r2) * NROWS + col] = acc[i][j][r2];
    }
}

// ---------- softmax in-place: row of S (fp32) -> bf16 P in first half of the same row ----------
__global__ __launch_bounds__(256) void softmax_inplace(float* __restrict__ S) {
  const int row = blockIdx.x, t = threadIdx.x;
  float* Sr = S + (size_t)row * NROWS;
  const float4* S4 = (const float4*)Sr;
  float4 v[4];
  float mx = -3.4e38f;
#pragma unroll
  for (int c = 0; c < 4; ++c) {
    v[c] = S4[c * 256 + t];
    mx = fmaxf(mx, fmaxf(fmaxf(v[c].x, v[c].y), fmaxf(v[c].z, v[c].w)));
  }
  __shared__ float red[4];
  for (int o = 32; o >= 1; o >>= 1) mx = fmaxf(mx, __shfl_xor(mx, o));
  int wv = t >> 6, ln = t & 63;
  if (ln == 0) red[wv] = mx;
  __syncthreads();
  mx = fmaxf(fmaxf(red[0], red[1]), fmaxf(red[2], red[3]));
  float s = 0.f;
#pragma unroll
  for (int c = 0; c < 4; ++c) {
    v[c].x = __expf(v[c].x - mx);
    v[c].y = __expf(v[c].y - mx);
    v[c].z = __expf(v[c].z - mx);
    v[c].w = __expf(v[c].w - mx);
    s += v[c].x + v[c].y + v[c].z + v[c].w;
  }
  for (int o = 32; o >= 1; o >>= 1) s += __shfl_xor(s, o);
  __syncthreads();
  if (ln == 0) red[wv] = s;
  __syncthreads();
  s = red[0] + red[1] + red[2] + red[3];
  float inv = 1.f / s;
  ushort4* P4 = (ushort4*)Sr;  // first 8KB of row; all fp32 reads happened pre-barrier
#pragma unroll
  for (int c = 0; c < 4; ++c) {
    ushort4 h;
    h.x = f2bf(v[c].x * inv);
    h.y = f2bf(v[c].y * inv);
    h.z = f2bf(v[c].z * inv);
    h.w = f2bf(v[c].w * inv);
    P4[c * 256 + t] = h;
  }
}

// ---------- Out_partial[z] = P * V over k-slice z; BM=128, split-K=2 ----------
__global__ __launch_bounds__(256) void gemm_pv(const ushort* __restrict__ P,
                                               const ushort* __restrict__ Vt,
                                               float* __restrict__ part) {
  extern __shared__ ushort sm[];
  const int n0 = blockIdx.x * 128, m0 = blockIdx.y * 128;
  const int kbeg = blockIdx.z * (NROWS / 2), kend = kbeg + NROWS / 2;
  float* dst = part + (size_t)blockIdx.z * NROWS * DDIM;
  const int t = threadIdx.x;
  const int wv = t >> 6, ln = t & 63;
  const int quad = ln >> 4, l16 = ln & 15;
  f32x4 acc[4][4];
#pragma unroll
  for (int i = 0; i < 4; ++i)
#pragma unroll
    for (int j = 0; j < 4; ++j) acc[i][j] = (f32x4){0.f, 0.f, 0.f, 0.f};
  gemm_core<128, false>(P, nullptr, Vt, nullptr, 2 * NROWS, NROWS, kbeg, kend, m0, n0, sm, acc);
#pragma unroll
  for (int i = 0; i < 4; ++i)
#pragma unroll
    for (int j = 0; j < 4; ++j) {
      int col = n0 + (wv & 1) * 64 + j * 16 + l16;
      int rw = m0 + (wv >> 1) * 64 + i * 16 + quad * 4;
#pragma unroll
      for (int r2 = 0; r2 < 4; ++r2)
        dst[(size_t)(rw + r2) * DDIM + col] = acc[i][j][r2];
    }
}

// ---------- Out = part0 + part1 ----------
__global__ __launch_bounds__(256) void add_partials(const float4* __restrict__ p0,
                                                    const float4* __restrict__ p1,
                                                    float4* __restrict__ out, int n4) {
  for (int i = blockIdx.x * 256 + threadIdx.x; i < n4; i += gridDim.x * 256) {
    float4 a = p0[i], b = p1[i];
    out[i] = (float4){a.x + b.x, a.y + b.y, a.z + b.z, a.w + b.w};
  }
}

extern "C" void kernel_launch(void* const* d_in, const int* in_sizes, int n_in,
                              void* d_out, int out_size, void* d_ws, size_t ws_size,
                              hipStream_t stream) {
  const float* x  = (const float*)d_in[0];
  const float* wq = (const float*)d_in[1];
  const float* wk = (const float*)d_in[2];
  const float* wv = (const float*)d_in[3];
  char* ws = (char*)d_ws;
  const size_t MB = 1u << 20;

  // Workspace map (peak 104 MiB):
  ushort* Vt  = (ushort*)(ws + 0);        // 0-8, written by qkv, alive through pv
  ushort* Qh  = (ushort*)(ws + 8 * MB);   // 8-40: Q/K split planes, dead after gemm_s
  ushort* Ql  = (ushort*)(ws + 16 * MB);
  ushort* Kh  = (ushort*)(ws + 24 * MB);
  ushort* Kl  = (ushort*)(ws + 32 * MB);
  float*  Pt0 = (float*)(ws + 8 * MB);    // 8-24:  pv partial 0 (aliases dead Qh/Ql)
  float*  Pt1 = (float*)(ws + 24 * MB);   // 24-40: pv partial 1 (aliases dead Kh/Kl)
  ushort* Xh  = (ushort*)(ws + 40 * MB);  // 40-56 (dead after qkv)
  ushort* Xl  = (ushort*)(ws + 48 * MB);
  ushort* Wqh = (ushort*)(ws + 56 * MB);  // 56-66: weight planes (dead after qkv)
  ushort* Wql = (ushort*)(ws + 58 * MB);
  ushort* Wkh = (ushort*)(ws + 60 * MB);
  ushort* Wkl = (ushort*)(ws + 62 * MB);
  ushort* Wvh = (ushort*)(ws + 64 * MB);
  float*  S   = (float*)(ws + 40 * MB);   // 40-104 (overwrites dead X/W)
  float*  Out = (float*)d_out;

  const int n4 = NROWS * DDIM / 4;

  prep<<<4096, 256, 0, stream>>>(x, wq, wk, wv, Xh, Xl, Wqh, Wql, Wkh, Wkl, Wvh);
  gemm_qkv<<<dim3(24, 32), 256, 32768, stream>>>(Xh, Xl, Wqh, Wql, Wkh, Wkl, Wvh,
                                                 Qh, Ql, Kh, Kl, Vt);
  gemm_s<<<dim3(32, 32), 256, 32768, stream>>>(Qh, Ql, Kh, Kl, S);
  softmax_inplace<<<NROWS, 256, 0, stream>>>(S);
  gemm_pv<<<dim3(8, 32, 2), 256, 16384, stream>>>((const ushort*)S, Vt, Pt0);
  add_partials<<<2048, 256, 0, stream>>>((const float4*)Pt0, (const float4*)Pt1,
                                         (float4*)Out, n4);
}

// Round 6
// 346.953 us; speedup vs baseline: 1.0590x; 1.0590x over previous
//
#include <hip/hip_runtime.h>
#include <math.h>

#define NROWS 4096
#define DDIM  1024

typedef __attribute__((ext_vector_type(8))) short short8;
typedef __attribute__((ext_vector_type(4))) float f32x4;

// ---------- bf16 helpers (manual RNE) ----------
__device__ __forceinline__ ushort f2bf(float v) {
  union { float f; uint32_t u; } c; c.f = v;
  uint32_t u = c.u;
  uint32_t lsb = (u >> 16) & 1u;
  u += 0x7fffu + lsb;
  return (ushort)(u >> 16);
}
__device__ __forceinline__ float bf2f(ushort h) {
  union { uint32_t u; float f; } c; c.u = ((uint32_t)h) << 16;
  return c.f;
}

// ---------- async global->LDS, 16B per lane (qkv staging only) ----------
__device__ __forceinline__ void gll16(const void* g, void* l) {
  __builtin_amdgcn_global_load_lds((const __attribute__((address_space(1))) void*)g,
                                   (__attribute__((address_space(3))) void*)l, 16, 0, 0);
}

// ---------- packed-fragment layout ----------
// Matrix [R][C] bf16 stored as 16x32 tiles of 1KB: tile T = (r>>4)*ldt + (c>>5)
// (ldt = C/32). Within tile: ushort index = ((c>>3)&3)*128 + (r&15)*8 + (c&7).
// A wave's MFMA fragment (rows r0..r0+15, cols c0..c0+31) is then the 1KB at
// T*512, lane ln reading 16B at T*512 + ln*8  (ln = quad*16 + l16).
__device__ __forceinline__ size_t pidx(int r, int c, int ldt) {
  return ((size_t)((r >> 4) * ldt + (c >> 5))) * 512 +
         ((c >> 3) & 3) * 128 + (r & 15) * 8 + (c & 7);
}

// ---------- prep: split x + transpose/split 3 weights (row-major outputs, qkv staging) ----
__global__ __launch_bounds__(256) void prep(const float* __restrict__ x,
                                            const float* __restrict__ wq,
                                            const float* __restrict__ wk,
                                            const float* __restrict__ wv,
                                            ushort* Xh, ushort* Xl,
                                            ushort* Wqh, ushort* Wql,
                                            ushort* Wkh, ushort* Wkl, ushort* Wvh) {
  __shared__ float tl[32][33];
  const int b = blockIdx.x, t = threadIdx.x;
  if (b < 1024) {
    const float4* src = (const float4*)x;
    ushort4* hi = (ushort4*)Xh;
    ushort4* lo = (ushort4*)Xl;
#pragma unroll
    for (int r = 0; r < 4; ++r) {
      int i = b * 1024 + r * 256 + t;
      float4 v = src[i];
      ushort4 h, l;
      h.x = f2bf(v.x); l.x = f2bf(v.x - bf2f(h.x));
      h.y = f2bf(v.y); l.y = f2bf(v.y - bf2f(h.y));
      h.z = f2bf(v.z); l.z = f2bf(v.z - bf2f(h.z));
      h.w = f2bf(v.w); l.w = f2bf(v.w - bf2f(h.w));
      hi[i] = h; lo[i] = l;
    }
  } else {
    const int z = (b - 1024) >> 10;
    const int tile = (b - 1024) & 1023;
    const float* src = z == 0 ? wq : (z == 1 ? wk : wv);
    ushort* dh = z == 0 ? Wqh : (z == 1 ? Wkh : Wvh);
    ushort* dl = z == 0 ? Wql : (z == 1 ? Wkl : nullptr);
    const int r0 = (tile >> 5) * 32;
    const int c0 = (tile & 31) * 32;
    const int tx = t & 31, ty = t >> 5;
    for (int i = ty; i < 32; i += 8)
      tl[i][tx] = src[(size_t)(r0 + i) * DDIM + c0 + tx];
    __syncthreads();
    for (int i = ty; i < 32; i += 8) {
      float v = tl[tx][i];
      ushort h = f2bf(v);
      size_t o = (size_t)(c0 + i) * DDIM + r0 + tx;
      dh[o] = h;
      if (dl) dl[o] = f2bf(v - bf2f(h));
    }
  }
}

// ---------- LDS-staged NT GEMM core (qkv only) ----------
template <int BM, bool SPLIT>
__device__ __forceinline__ void gemm_core(const ushort* __restrict__ Ah,
                                          const ushort* __restrict__ Al,
                                          const ushort* __restrict__ Bh,
                                          const ushort* __restrict__ Bl,
                                          int lda, int ldb, int kbeg, int kend,
                                          int m0, int n0, ushort* sm,
                                          f32x4 (*acc)[4]) {
  constexpr int MI = BM / 32;
  constexpr int ATILE = BM * 32;
  constexpr int BTILE = 128 * 32;
  ushort* sAh = sm;
  ushort* sAl = SPLIT ? sm + ATILE : nullptr;
  ushort* sBh = sm + (SPLIT ? 2 * ATILE : ATILE);
  ushort* sBl = SPLIT ? sBh + BTILE : nullptr;

  const int t = threadIdx.x;
  const int wv = t >> 6, ln = t & 63;
  const int quad = ln >> 4, l16 = ln & 15;
  const int key = (l16 >> 1) & 3;
  const int arb = (wv >> 1) * (BM / 2);
  const int crb = (wv & 1) * 64;

  for (int k0 = kbeg; k0 < kend; k0 += 32) {
#pragma unroll
    for (int r = 0; r < BM * 64 / 4096; ++r) {
      int f = t * 16 + r * 4096;
      int row = f >> 6;
      int srcq = ((f >> 4) & 3) ^ ((row >> 1) & 3);
      size_t go = (size_t)(m0 + row) * lda + k0 + srcq * 8;
      gll16(Ah + go, sAh + (f >> 1));
      if (SPLIT) gll16(Al + go, sAl + (f >> 1));
    }
#pragma unroll
    for (int r = 0; r < 2; ++r) {
      int f = t * 16 + r * 4096;
      int row = f >> 6;
      int srcq = ((f >> 4) & 3) ^ ((row >> 1) & 3);
      size_t go = (size_t)(n0 + row) * ldb + k0 + srcq * 8;
      gll16(Bh + go, sBh + (f >> 1));
      if (SPLIT) gll16(Bl + go, sBl + (f >> 1));
    }
    __syncthreads();

    short8 ah[MI], bh[4], al[MI], bl[4];
#pragma unroll
    for (int i = 0; i < MI; ++i) {
      int off = (arb + i * 16 + l16) * 32 + (quad ^ key) * 8;
      ah[i] = *(const short8*)(sAh + off);
      if (SPLIT) al[i] = *(const short8*)(sAl + off);
    }
#pragma unroll
    for (int j = 0; j < 4; ++j) {
      int off = (crb + j * 16 + l16) * 32 + (quad ^ key) * 8;
      bh[j] = *(const short8*)(sBh + off);
      if (SPLIT) bl[j] = *(const short8*)(sBl + off);
    }
#pragma unroll
    for (int i = 0; i < MI; ++i)
#pragma unroll
      for (int j = 0; j < 4; ++j) {
        acc[i][j] = __builtin_amdgcn_mfma_f32_16x16x32_bf16(ah[i], bh[j], acc[i][j], 0, 0, 0);
        if (SPLIT) {
          acc[i][j] = __builtin_amdgcn_mfma_f32_16x16x32_bf16(ah[i], bl[j], acc[i][j], 0, 0, 0);
          acc[i][j] = __builtin_amdgcn_mfma_f32_16x16x32_bf16(al[i], bh[j], acc[i][j], 0, 0, 0);
        }
      }
    __syncthreads();
  }
}

// ---------- fused QKV: epilogues write PACKED Q/K (split) and PACKED Vt ----------
__global__ __launch_bounds__(256) void gemm_qkv(const ushort* __restrict__ Xh,
                                                const ushort* __restrict__ Xl,
                                                const ushort* __restrict__ Wqh, const ushort* __restrict__ Wql,
                                                const ushort* __restrict__ Wkh, const ushort* __restrict__ Wkl,
                                                const ushort* __restrict__ Wvh,
                                                ushort* Qh, ushort* Ql, ushort* Kh, ushort* Kl, ushort* Vt) {
  extern __shared__ ushort sm[];
  const int which = blockIdx.x % 3;
  const int g = blockIdx.x / 3;              // 0..7
  const int t = threadIdx.x;
  const int wv = t >> 6, ln = t & 63;
  const int quad = ln >> 4, l16 = ln & 15;

  f32x4 acc[4][4];
#pragma unroll
  for (int i = 0; i < 4; ++i)
#pragma unroll
    for (int j = 0; j < 4; ++j) acc[i][j] = (f32x4){0.f, 0.f, 0.f, 0.f};

  if (which == 2) {
    // Vt[d][kv] = sum_k Wvh[d][k] * Xh[kv][k]   (= V[kv][d]) -> packed, ldt = 4096/32
    const int m0 = g * 128;                  // d over 1024
    const int n0 = blockIdx.y * 128;         // kv over 4096
    gemm_core<128, false>(Wvh, nullptr, Xh, nullptr, DDIM, DDIM, 0, DDIM, m0, n0, sm, acc);
#pragma unroll
    for (int i = 0; i < 4; ++i)
#pragma unroll
      for (int j = 0; j < 4; ++j) {
        int kv = n0 + (wv & 1) * 64 + j * 16 + l16;
        int d = m0 + (wv >> 1) * 64 + i * 16 + quad * 4;
#pragma unroll
        for (int r2 = 0; r2 < 4; ++r2)
          Vt[pidx(d + r2, kv, NROWS / 32)] = f2bf(acc[i][j][r2]);
      }
  } else {
    const int n0 = g * 128;                  // d over 1024
    const int m0 = blockIdx.y * 128;         // rows over 4096
    const ushort* Bh = which ? Wkh : Wqh;
    const ushort* Bl = which ? Wkl : Wql;
    gemm_core<128, true>(Xh, Xl, Bh, Bl, DDIM, DDIM, 0, DDIM, m0, n0, sm, acc);
    const float scale = which ? 1.0f : 0.03125f;  // fold 1/sqrt(1024) into Q
    ushort* H = which ? Kh : Qh;
    ushort* L = which ? Kl : Ql;
#pragma unroll
    for (int i = 0; i < 4; ++i)
#pragma unroll
      for (int j = 0; j < 4; ++j) {
        int col = n0 + (wv & 1) * 64 + j * 16 + l16;
        int rw = m0 + (wv >> 1) * 64 + i * 16 + quad * 4;
#pragma unroll
        for (int r2 = 0; r2 < 4; ++r2) {
          float v = acc[i][j][r2] * scale;
          ushort h = f2bf(v);
          size_t o = pidx(rw + r2, col, DDIM / 32);
          H[o] = h;
          L[o] = f2bf(v - bf2f(h));
        }
      }
  }
}

// ---------- S = Q*K^T (split), LDS-free, barrier-free: packed-frag direct loads ----------
__global__ __launch_bounds__(256) void gemm_s(const ushort* __restrict__ Qh, const ushort* __restrict__ Ql,
                                              const ushort* __restrict__ Kh, const ushort* __restrict__ Kl,
                                              float* __restrict__ S) {
  const int n0 = blockIdx.x * 128, m0 = blockIdx.y * 128;
  const int t = threadIdx.x;
  const int wv = t >> 6, ln = t & 63;
  const int quad = ln >> 4, l16 = ln & 15;
  const int arb = (wv >> 1) * 64, crb = (wv & 1) * 64;
  const int ra = (m0 + arb) >> 4;   // A tile-row base (frags ra..ra+3)
  const int rb = (n0 + crb) >> 4;

  f32x4 acc[4][4];
#pragma unroll
  for (int i = 0; i < 4; ++i)
#pragma unroll
    for (int j = 0; j < 4; ++j) acc[i][j] = (f32x4){0.f, 0.f, 0.f, 0.f};

  // tile-row stride = 32 tiles (K=1024) * 512 ushorts
  size_t baseA[4], baseB[4];
#pragma unroll
  for (int i = 0; i < 4; ++i) baseA[i] = (size_t)(ra + i) * 16384 + ln * 8;
#pragma unroll
  for (int j = 0; j < 4; ++j) baseB[j] = (size_t)(rb + j) * 16384 + ln * 8;

#pragma unroll 2
  for (int s = 0; s < 32; ++s) {
    short8 ah[4], al[4];
#pragma unroll
    for (int i = 0; i < 4; ++i) {
      size_t o = baseA[i] + (size_t)s * 512;
      ah[i] = *(const short8*)(Qh + o);
      al[i] = *(const short8*)(Ql + o);
    }
#pragma unroll
    for (int j = 0; j < 4; ++j) {
      size_t o = baseB[j] + (size_t)s * 512;
      short8 bh = *(const short8*)(Kh + o);
      short8 bl = *(const short8*)(Kl + o);
#pragma unroll
      for (int i = 0; i < 4; ++i) {
        acc[i][j] = __builtin_amdgcn_mfma_f32_16x16x32_bf16(ah[i], bh, acc[i][j], 0, 0, 0);
        acc[i][j] = __builtin_amdgcn_mfma_f32_16x16x32_bf16(ah[i], bl, acc[i][j], 0, 0, 0);
        acc[i][j] = __builtin_amdgcn_mfma_f32_16x16x32_bf16(al[i], bh, acc[i][j], 0, 0, 0);
      }
    }
  }

#pragma unroll
  for (int i = 0; i < 4; ++i)
#pragma unroll
    for (int j = 0; j < 4; ++j) {
      int col = n0 + crb + j * 16 + l16;
      int rw = m0 + arb + i * 16 + quad * 4;
#pragma unroll
      for (int r2 = 0; r2 < 4; ++r2)
        S[(size_t)(rw + r2) * NROWS + col] = acc[i][j][r2];
    }
}

// ---------- softmax: row of S (fp32) -> PACKED bf16 P ----------
__global__ __launch_bounds__(256) void softmax_pack(const float* __restrict__ S,
                                                    ushort* __restrict__ P) {
  const int row = blockIdx.x, t = threadIdx.x;
  const float* Sr = S + (size_t)row * NROWS;
  const float4* S4 = (const float4*)Sr;
  float4 v[4];
  float mx = -3.4e38f;
#pragma unroll
  for (int c = 0; c < 4; ++c) {
    v[c] = S4[c * 256 + t];
    mx = fmaxf(mx, fmaxf(fmaxf(v[c].x, v[c].y), fmaxf(v[c].z, v[c].w)));
  }
  __shared__ float red[4];
  for (int o = 32; o >= 1; o >>= 1) mx = fmaxf(mx, __shfl_xor(mx, o));
  int wv = t >> 6, ln = t & 63;
  if (ln == 0) red[wv] = mx;
  __syncthreads();
  mx = fmaxf(fmaxf(red[0], red[1]), fmaxf(red[2], red[3]));
  float s = 0.f;
#pragma unroll
  for (int c = 0; c < 4; ++c) {
    v[c].x = __expf(v[c].x - mx);
    v[c].y = __expf(v[c].y - mx);
    v[c].z = __expf(v[c].z - mx);
    v[c].w = __expf(v[c].w - mx);
    s += v[c].x + v[c].y + v[c].z + v[c].w;
  }
  for (int o = 32; o >= 1; o >>= 1) s += __shfl_xor(s, o);
  __syncthreads();
  if (ln == 0) red[wv] = s;
  __syncthreads();
  s = red[0] + red[1] + red[2] + red[3];
  float inv = 1.f / s;
#pragma unroll
  for (int c = 0; c < 4; ++c) {
    ushort4 h;
    h.x = f2bf(v[c].x * inv);
    h.y = f2bf(v[c].y * inv);
    h.z = f2bf(v[c].z * inv);
    h.w = f2bf(v[c].w * inv);
    int c0 = 1024 * c + 4 * t;            // 4 consecutive cols, 8B-aligned in packed space
    *(ushort4*)(P + pidx(row, c0, NROWS / 32)) = h;
  }
}

// ---------- Out = P*V, LDS-free, barrier-free; BM=64 (512 blocks) ----------
__global__ __launch_bounds__(256) void gemm_pv(const ushort* __restrict__ P,
                                               const ushort* __restrict__ Vt,
                                               float* __restrict__ Out) {
  const int n0 = blockIdx.x * 128, m0 = blockIdx.y * 64;
  const int t = threadIdx.x;
  const int wv = t >> 6, ln = t & 63;
  const int quad = ln >> 4, l16 = ln & 15;
  const int arb = (wv >> 1) * 32, crb = (wv & 1) * 64;
  const int ra = (m0 + arb) >> 4;
  const int rb = (n0 + crb) >> 4;

  f32x4 acc[2][4];
#pragma unroll
  for (int i = 0; i < 2; ++i)
#pragma unroll
    for (int j = 0; j < 4; ++j) acc[i][j] = (f32x4){0.f, 0.f, 0.f, 0.f};

  // K=4096 -> 128 tiles per stripe; stripe stride = 128*512 = 65536 ushorts
  size_t baseA[2], baseB[4];
#pragma unroll
  for (int i = 0; i < 2; ++i) baseA[i] = (size_t)(ra + i) * 65536 + ln * 8;
#pragma unroll
  for (int j = 0; j < 4; ++j) baseB[j] = (size_t)(rb + j) * 65536 + ln * 8;

#pragma unroll 2
  for (int s = 0; s < 128; ++s) {
    short8 a0 = *(const short8*)(P + baseA[0] + (size_t)s * 512);
    short8 a1 = *(const short8*)(P + baseA[1] + (size_t)s * 512);
#pragma unroll
    for (int j = 0; j < 4; ++j) {
      short8 b = *(const short8*)(Vt + baseB[j] + (size_t)s * 512);
      acc[0][j] = __builtin_amdgcn_mfma_f32_16x16x32_bf16(a0, b, acc[0][j], 0, 0, 0);
      acc[1][j] = __builtin_amdgcn_mfma_f32_16x16x32_bf16(a1, b, acc[1][j], 0, 0, 0);
    }
  }

#pragma unroll
  for (int i = 0; i < 2; ++i)
#pragma unroll
    for (int j = 0; j < 4; ++j) {
      int col = n0 + crb + j * 16 + l16;
      int rw = m0 + arb + i * 16 + quad * 4;
#pragma unroll
      for (int r2 = 0; r2 < 4; ++r2)
        Out[(size_t)(rw + r2) * DDIM + col] = acc[i][j][r2];
    }
}

extern "C" void kernel_launch(void* const* d_in, const int* in_sizes, int n_in,
                              void* d_out, int out_size, void* d_ws, size_t ws_size,
                              hipStream_t stream) {
  const float* x  = (const float*)d_in[0];
  const float* wq = (const float*)d_in[1];
  const float* wk = (const float*)d_in[2];
  const float* wv = (const float*)d_in[3];
  char* ws = (char*)d_ws;
  const size_t MB = 1u << 20;

  // Workspace map (peak 104 MiB):
  ushort* Vt  = (ushort*)(ws + 0);        // 0-8   packed, alive through pv
  ushort* Qh  = (ushort*)(ws + 8 * MB);   // 8-40  packed Q/K planes, dead after gemm_s
  ushort* Ql  = (ushort*)(ws + 16 * MB);
  ushort* Kh  = (ushort*)(ws + 24 * MB);
  ushort* Kl  = (ushort*)(ws + 32 * MB);
  ushort* Pp  = (ushort*)(ws + 8 * MB);   // 8-40  packed P (aliases dead Q/K)
  ushort* Xh  = (ushort*)(ws + 40 * MB);  // 40-56 row-major (dead after qkv)
  ushort* Xl  = (ushort*)(ws + 48 * MB);
  ushort* Wqh = (ushort*)(ws + 56 * MB);  // 56-66 row-major weights (dead after qkv)
  ushort* Wql = (ushort*)(ws + 58 * MB);
  ushort* Wkh = (ushort*)(ws + 60 * MB);
  ushort* Wkl = (ushort*)(ws + 62 * MB);
  ushort* Wvh = (ushort*)(ws + 64 * MB);
  float*  S   = (float*)(ws + 40 * MB);   // 40-104 (overwrites dead X/W)
  float*  Out = (float*)d_out;

  prep<<<4096, 256, 0, stream>>>(x, wq, wk, wv, Xh, Xl, Wqh, Wql, Wkh, Wkl, Wvh);
  gemm_qkv<<<dim3(24, 32), 256, 32768, stream>>>(Xh, Xl, Wqh, Wql, Wkh, Wkl, Wvh,
                                                 Qh, Ql, Kh, Kl, Vt);
  gemm_s<<<dim3(32, 32), 256, 0, stream>>>(Qh, Ql, Kh, Kl, S);
  softmax_pack<<<NROWS, 256, 0, stream>>>(S, Pp);
  gemm_pv<<<dim3(8, 64), 256, 0, stream>>>(Pp, Vt, Out);
}